// Round 1
// baseline (11989.879 us; speedup 1.0000x reference)
//
#include <hip/hip_runtime.h>

// Muskingum-Cunge routing on a full binary tree (heap layout), depth 13.
// N = 8191 reaches, T = 2048 timesteps. Outlet = node 0.
// Round 1: single-workgroup persistent kernel (correctness + calibration).

#define NN 8191
#define TT 2048
#define NTHREADS 1024

#if __has_builtin(__builtin_amdgcn_exp2f)
__device__ __forceinline__ float fexp2(float x) { return __builtin_amdgcn_exp2f(x); }
#else
__device__ __forceinline__ float fexp2(float x) { return exp2f(x); }
#endif
#if __has_builtin(__builtin_amdgcn_logf)
__device__ __forceinline__ float flog2(float x) { return __builtin_amdgcn_logf(x); }
#else
__device__ __forceinline__ float flog2(float x) { return log2f(x); }
#endif
#if __has_builtin(__builtin_amdgcn_rcpf)
__device__ __forceinline__ float frcp(float x) { return __builtin_amdgcn_rcpf(x); }
#else
__device__ __forceinline__ float frcp(float x) { return 1.0f / x; }
#endif

// One variable-parameter Muskingum-Cunge update.
//  Derived per-reach constants:
//   cc  = (5/3) * dc^(2/3) * sqrt(S) / n     (so c = max(cc * Qr^(2de/3), 1e-3))
//   e23 = (2/3) * de
//   twoL = 2*L, SL = S*L
__device__ __forceinline__ float mc_update(float Inew, float Iold, float Oold,
                                           float cc, float e23, float wc, float we,
                                           float twoL, float SL, float dtf)
{
    float Qr = fmaxf(0.5f * (Inew + Oold), 1e-3f);
    float lg = flog2(Qr);
    float c  = fmaxf(cc * fexp2(e23 * lg), 1e-3f);
    float w  = wc * fexp2(we * lg);
    float twoK = twoL * frcp(c);
    float X = 0.5f - 0.5f * Qr * frcp(w * SL * c);
    X = fminf(fmaxf(X, 0.0f), 0.5f);
    float A = twoK * X;           // 2*K*X
    float B = twoK - A;           // 2*K*(1-X)
    float r = frcp(B + dtf);      // 1/den
    float C1 = (dtf - A) * r;
    float C2 = (dtf + A) * r;
    float C3 = (B - dtf) * r;
    return fmaxf(C1 * Inew + C2 * Iold + C3 * Oold, 0.0f);
}

__global__ __launch_bounds__(NTHREADS)
void route_kernel(const float* __restrict__ lat,   // [T*N]
                  const float* __restrict__ nman,  // [N]
                  const float* __restrict__ len,   // [N]
                  const float* __restrict__ slp,   // [N]
                  const float* __restrict__ wcf,   // [N]
                  const float* __restrict__ wex,   // [N]
                  const float* __restrict__ dcf,   // [N]
                  const float* __restrict__ dex,   // [N]
                  const int*   __restrict__ dtp,   // [1]
                  float*       __restrict__ out)   // [T]
{
    __shared__ float Osh[NN];
    const int tid = threadIdx.x;
    const float dtf = (float)dtp[0];

    // Static node ownership (heap indices):
    //  slot 0..3 : level 12 nodes 4095 + k*1024 + tid
    //  slot 4..5 : level 11 nodes 2047 + k*1024 + tid
    //  slot 6    : level 10 node  1023 + tid
    //  slot 7    : node tid (levels 0..9), valid for tid < 1023
    int nodes[8];
    nodes[0] = 4095 + tid;
    nodes[1] = 5119 + tid;
    nodes[2] = 6143 + tid;
    nodes[3] = 7167 + tid;
    nodes[4] = 2047 + tid;
    nodes[5] = 3071 + tid;
    nodes[6] = 1023 + tid;
    nodes[7] = (tid < 1023) ? tid : 0;   // dummy for tid==1023 (never used)

    float cc[8], e23[8], wcc[8], wee[8], twoL[8], SL[8];
    float Ireg[8], Oreg[8];
#pragma unroll
    for (int k = 0; k < 8; ++k) {
        int i = nodes[k];
        float n = nman[i], L = len[i], S = slp[i];
        float wc = wcf[i], we = wex[i], dc = dcf[i], de = dex[i];
        float sqrtS = sqrtf(S);
        float dc23 = fexp2(0.6666667f * flog2(dc));  // dc^(2/3), dc in [0.2,0.5]
        cc[k]  = 1.6666667f * dc23 * sqrtS * frcp(n);
        e23[k] = 0.6666667f * de;
        wcc[k] = wc;
        wee[k] = we;
        twoL[k] = 2.0f * L;
        SL[k]  = S * L;
        Ireg[k] = 0.0f;
        Oreg[k] = 0.0f;
    }

    // Zero LDS outflows (deterministic start; also harmless).
    for (int i = tid; i < NN; i += NTHREADS) Osh[i] = 0.0f;
    __syncthreads();

    for (int t = 0; t < TT; ++t) {
        const float* __restrict__ latt = lat + (size_t)t * NN;

        // ---- level 12 (headwaters, no upstream) ----
#pragma unroll
        for (int k = 0; k < 4; ++k) {
            int i = nodes[k];
            float Inew = latt[i];
            float O = mc_update(Inew, Ireg[k], Oreg[k],
                                cc[k], e23[k], wcc[k], wee[k], twoL[k], SL[k], dtf);
            Ireg[k] = Inew; Oreg[k] = O; Osh[i] = O;
        }
        __syncthreads();

        // ---- level 11 ----
#pragma unroll
        for (int k = 4; k < 6; ++k) {
            int i = nodes[k];
            float Inew = latt[i] + Osh[2 * i + 1] + Osh[2 * i + 2];
            float O = mc_update(Inew, Ireg[k], Oreg[k],
                                cc[k], e23[k], wcc[k], wee[k], twoL[k], SL[k], dtf);
            Ireg[k] = Inew; Oreg[k] = O; Osh[i] = O;
        }
        __syncthreads();

        // ---- level 10 ----
        {
            int i = nodes[6];
            float Inew = latt[i] + Osh[2 * i + 1] + Osh[2 * i + 2];
            float O = mc_update(Inew, Ireg[6], Oreg[6],
                                cc[6], e23[6], wcc[6], wee[6], twoL[6], SL[6], dtf);
            Ireg[6] = Inew; Oreg[6] = O; Osh[i] = O;
        }
        __syncthreads();

        // ---- levels 9..0 : node == tid ----
        for (int l = 9; l >= 0; --l) {
            int s = (1 << l) - 1;
            int e = (1 << (l + 1)) - 1;
            if (tid >= s && tid < e) {
                int i = tid;
                float Inew = latt[i] + Osh[2 * i + 1] + Osh[2 * i + 2];
                float O = mc_update(Inew, Ireg[7], Oreg[7],
                                    cc[7], e23[7], wcc[7], wee[7], twoL[7], SL[7], dtf);
                Ireg[7] = Inew; Oreg[7] = O; Osh[i] = O;
            }
            __syncthreads();
        }

        if (tid == 0) out[t] = Oreg[7];   // node 0 outflow this timestep
    }
}

extern "C" void kernel_launch(void* const* d_in, const int* in_sizes, int n_in,
                              void* d_out, int out_size, void* d_ws, size_t ws_size,
                              hipStream_t stream) {
    const float* lat  = (const float*)d_in[0];
    const float* nman = (const float*)d_in[1];
    const float* len  = (const float*)d_in[2];
    const float* slp  = (const float*)d_in[3];
    const float* wcf  = (const float*)d_in[4];
    const float* wex  = (const float*)d_in[5];
    const float* dcf  = (const float*)d_in[6];
    const float* dex  = (const float*)d_in[7];
    const int*   dtp  = (const int*)d_in[8];
    float* out = (float*)d_out;

    route_kernel<<<dim3(1), dim3(NTHREADS), 0, stream>>>(
        lat, nman, len, slp, wcf, wex, dcf, dex, dtp, out);
}

// Round 2
// 1747.850 us; speedup vs baseline: 6.8598x; 6.8598x over previous
//
#include <hip/hip_runtime.h>

// Muskingum-Cunge routing on a full binary tree (heap layout), depth 13.
// N = 8191 reaches, T = 2048 timesteps. Outlet = node 0.
// Round 2: persistent cross-CU pipeline over timesteps.
//   24 blocks, one per level-chunk (L12 x8, L11 x4, L10 x2, L9..L0 x1).
//   Stage state (I_old, O_old, derived params) lives in registers.
//   Communication: full-size per-level outflow buffers in d_ws + monotone
//   done-counters (release/acquire, agent scope). Batch B=16 timesteps per
//   handoff; per-batch prefetch of child/lat loads.
// Fallback: single-WG kernel (round-1, verified) if ws_size too small.

#define NN 8191
#define TT 2048
#define BATCH 16
#define NBLK 24
#define PIPE_THREADS 512

#define FLAGS_FOFF 16775168ull              // float offset of flags region in ws
#define REQ_BYTES  ((FLAGS_FOFF + NBLK * 64ull) * 4ull)   // 67,106,816

#if __has_builtin(__builtin_amdgcn_exp2f)
__device__ __forceinline__ float fexp2(float x) { return __builtin_amdgcn_exp2f(x); }
#else
__device__ __forceinline__ float fexp2(float x) { return exp2f(x); }
#endif
#if __has_builtin(__builtin_amdgcn_logf)
__device__ __forceinline__ float flog2(float x) { return __builtin_amdgcn_logf(x); }
#else
__device__ __forceinline__ float flog2(float x) { return log2f(x); }
#endif
#if __has_builtin(__builtin_amdgcn_rcpf)
__device__ __forceinline__ float frcp(float x) { return __builtin_amdgcn_rcpf(x); }
#else
__device__ __forceinline__ float frcp(float x) { return 1.0f / x; }
#endif

__device__ __forceinline__ float mc_update(float Inew, float Iold, float Oold,
                                           float cc, float e23, float wc, float we,
                                           float twoL, float SL, float dtf)
{
    float Qr = fmaxf(0.5f * (Inew + Oold), 1e-3f);
    float lg = flog2(Qr);
    float c  = fmaxf(cc * fexp2(e23 * lg), 1e-3f);
    float w  = wc * fexp2(we * lg);
    float twoK = twoL * frcp(c);
    float X = 0.5f - 0.5f * Qr * frcp(w * SL * c);
    X = fminf(fmaxf(X, 0.0f), 0.5f);
    float A = twoK * X;
    float B = twoK - A;
    float r = frcp(B + dtf);
    float C1 = (dtf - A) * r;
    float C2 = (dtf + A) * r;
    float C3 = (B - dtf) * r;
    return fmaxf(C1 * Inew + C2 * Iold + C3 * Oold, 0.0f);
}

// ---------------- stage tables ----------------
__constant__ int g_level[NBLK] = {12,12,12,12,12,12,12,12, 11,11,11,11, 10,10,
                                   9, 8, 7, 6, 5, 4, 3, 2, 1, 0};
__constant__ int g_nstart[NBLK] = {4095,4607,5119,5631,6143,6655,7167,7679,
                                   2047,2559,3071,3583, 1023,1535,
                                   511, 255, 127, 63, 31, 15, 7, 3, 1, 0};
__constant__ int g_cnt[NBLK] = {512,512,512,512,512,512,512,512,
                                512,512,512,512, 512,512,
                                512, 256, 128, 64, 32, 16, 8, 4, 2, 1};
__constant__ int g_prodA[NBLK] = {-1,-1,-1,-1,-1,-1,-1,-1,
                                  0, 2, 4, 6, 8, 10,
                                  12, 14, 15, 16, 17, 18, 19, 20, 21, 22};
__constant__ int g_prodB[NBLK] = {-1,-1,-1,-1,-1,-1,-1,-1,
                                  1, 3, 5, 7, 9, 11,
                                  13, -1, -1, -1, -1, -1, -1, -1, -1, -1};
// float offset of level-l output buffer inside ws (levels 0..12)
__constant__ unsigned long long g_off[13] = {
    16773120ull, 16769024ull, 16760832ull, 16744448ull, 16711680ull,
    16646144ull, 16515072ull, 16252928ull, 15728640ull, 14680064ull,
    12582912ull, 8388608ull, 0ull};

__device__ __forceinline__ void waitflag(const unsigned int* f, unsigned int target)
{
    while (__hip_atomic_load(f, __ATOMIC_ACQUIRE, __HIP_MEMORY_SCOPE_AGENT) < target) {
        __builtin_amdgcn_s_sleep(1);
    }
}

__global__ void zero_flags(unsigned int* flags)
{
    for (int i = threadIdx.x; i < NBLK * 64; i += blockDim.x) flags[i] = 0;
}

__global__ __launch_bounds__(PIPE_THREADS)
void pipe_kernel(const float* __restrict__ lat,
                 const float* __restrict__ nman,
                 const float* __restrict__ len,
                 const float* __restrict__ slp,
                 const float* __restrict__ wcf,
                 const float* __restrict__ wex,
                 const float* __restrict__ dcf,
                 const float* __restrict__ dex,
                 const int*   __restrict__ dtp,
                 float*       __restrict__ out,
                 float*       __restrict__ ws)
{
    const int bid = blockIdx.x;
    const int tid = threadIdx.x;
    const int lvl = g_level[bid];
    const int cnt = g_cnt[bid];
    const bool multiwave = (cnt > 64);
    if (!multiwave && tid >= 64) return;   // single-wave stages: shed extra waves

    const int nstart = g_nstart[bid];
    const bool active = (tid < cnt);
    const int node = active ? (nstart + tid) : nstart;

    unsigned int* flags = (unsigned int*)(ws + FLAGS_FOFF);
    unsigned int* myflag = flags + (size_t)bid * 64;
    const int pa = g_prodA[bid], pb = g_prodB[bid];
    const unsigned int* fa = (pa >= 0) ? (flags + (size_t)pa * 64) : nullptr;
    const unsigned int* fb = (pb >= 0) ? (flags + (size_t)pb * 64) : nullptr;

    const bool haschild = (lvl < 12);
    const int myW = 1 << lvl;
    const int childW = 1 << (lvl + 1);
    float* myBuf = ws + g_off[lvl];
    const float* childBuf = haschild ? (ws + g_off[lvl + 1]) : nullptr;
    const int mylocal = nstart - (myW - 1) + tid;

    const float dtf = (float)dtp[0];

    // per-node derived constants + state (registers, persistent)
    float cc = 0, e23 = 0, wcc = 0, wee = 0, twoL = 0, SL = 0;
    float Iold = 0.0f, Oold = 0.0f;
    {
        float n = nman[node], L = len[node], S = slp[node];
        float wc = wcf[node], we = wex[node], dc = dcf[node], de = dex[node];
        float dc23 = fexp2(0.6666667f * flog2(dc));
        cc  = 1.6666667f * dc23 * sqrtf(S) * frcp(n);
        e23 = 0.6666667f * de;
        wcc = wc; wee = we;
        twoL = 2.0f * L;
        SL = S * L;
    }

    for (int t0 = 0; t0 < TT; t0 += BATCH) {
        if (fa) waitflag(fa, (unsigned int)(t0 + BATCH));
        if (fb) waitflag(fb, (unsigned int)(t0 + BATCH));

        float la[BATCH], c0[BATCH], c1[BATCH];
        if (active) {
#pragma unroll
            for (int k = 0; k < BATCH; ++k) {
                la[k] = lat[(size_t)(t0 + k) * NN + node];
                if (haschild) {
                    const float2 c = *(const float2*)(childBuf +
                        (size_t)(t0 + k) * childW + 2 * mylocal);
                    c0[k] = c.x; c1[k] = c.y;
                }
            }
#pragma unroll
            for (int k = 0; k < BATCH; ++k) {
                float Inew = la[k] + (haschild ? (c0[k] + c1[k]) : 0.0f);
                float O = mc_update(Inew, Iold, Oold, cc, e23, wcc, wee, twoL, SL, dtf);
                Iold = Inew; Oold = O;
                if (lvl > 0) myBuf[(size_t)(t0 + k) * myW + mylocal] = O;
                else         out[t0 + k] = O;
            }
        }
        // publish: all threads fence, then one thread bumps the counter
        __threadfence();
        if (multiwave) __syncthreads();
        if (tid == 0)
            __hip_atomic_store(myflag, (unsigned int)(t0 + BATCH),
                               __ATOMIC_RELEASE, __HIP_MEMORY_SCOPE_AGENT);
    }
}

// ---------------- fallback: round-1 single-WG kernel (verified) ----------------
#define NTHREADS 1024
__global__ __launch_bounds__(NTHREADS)
void route_kernel(const float* __restrict__ lat,
                  const float* __restrict__ nman,
                  const float* __restrict__ len,
                  const float* __restrict__ slp,
                  const float* __restrict__ wcf,
                  const float* __restrict__ wex,
                  const float* __restrict__ dcf,
                  const float* __restrict__ dex,
                  const int*   __restrict__ dtp,
                  float*       __restrict__ out)
{
    __shared__ float Osh[NN];
    const int tid = threadIdx.x;
    const float dtf = (float)dtp[0];

    int nodes[8];
    nodes[0] = 4095 + tid;
    nodes[1] = 5119 + tid;
    nodes[2] = 6143 + tid;
    nodes[3] = 7167 + tid;
    nodes[4] = 2047 + tid;
    nodes[5] = 3071 + tid;
    nodes[6] = 1023 + tid;
    nodes[7] = (tid < 1023) ? tid : 0;

    float cc[8], e23[8], wcc[8], wee[8], twoL[8], SL[8];
    float Ireg[8], Oreg[8];
#pragma unroll
    for (int k = 0; k < 8; ++k) {
        int i = nodes[k];
        float n = nman[i], L = len[i], S = slp[i];
        float wc = wcf[i], we = wex[i], dc = dcf[i], de = dex[i];
        float dc23 = fexp2(0.6666667f * flog2(dc));
        cc[k]  = 1.6666667f * dc23 * sqrtf(S) * frcp(n);
        e23[k] = 0.6666667f * de;
        wcc[k] = wc; wee[k] = we;
        twoL[k] = 2.0f * L;
        SL[k]  = S * L;
        Ireg[k] = 0.0f; Oreg[k] = 0.0f;
    }
    for (int i = tid; i < NN; i += NTHREADS) Osh[i] = 0.0f;
    __syncthreads();

    for (int t = 0; t < TT; ++t) {
        const float* __restrict__ latt = lat + (size_t)t * NN;
#pragma unroll
        for (int k = 0; k < 4; ++k) {
            int i = nodes[k];
            float Inew = latt[i];
            float O = mc_update(Inew, Ireg[k], Oreg[k],
                                cc[k], e23[k], wcc[k], wee[k], twoL[k], SL[k], dtf);
            Ireg[k] = Inew; Oreg[k] = O; Osh[i] = O;
        }
        __syncthreads();
#pragma unroll
        for (int k = 4; k < 6; ++k) {
            int i = nodes[k];
            float Inew = latt[i] + Osh[2 * i + 1] + Osh[2 * i + 2];
            float O = mc_update(Inew, Ireg[k], Oreg[k],
                                cc[k], e23[k], wcc[k], wee[k], twoL[k], SL[k], dtf);
            Ireg[k] = Inew; Oreg[k] = O; Osh[i] = O;
        }
        __syncthreads();
        {
            int i = nodes[6];
            float Inew = latt[i] + Osh[2 * i + 1] + Osh[2 * i + 2];
            float O = mc_update(Inew, Ireg[6], Oreg[6],
                                cc[6], e23[6], wcc[6], wee[6], twoL[6], SL[6], dtf);
            Ireg[6] = Inew; Oreg[6] = O; Osh[i] = O;
        }
        __syncthreads();
        for (int l = 9; l >= 0; --l) {
            int s = (1 << l) - 1;
            int e = (1 << (l + 1)) - 1;
            if (tid >= s && tid < e) {
                int i = tid;
                float Inew = latt[i] + Osh[2 * i + 1] + Osh[2 * i + 2];
                float O = mc_update(Inew, Ireg[7], Oreg[7],
                                    cc[7], e23[7], wcc[7], wee[7], twoL[7], SL[7], dtf);
                Ireg[7] = Inew; Oreg[7] = O; Osh[i] = O;
            }
            __syncthreads();
        }
        if (tid == 0) out[t] = Oreg[7];
    }
}

extern "C" void kernel_launch(void* const* d_in, const int* in_sizes, int n_in,
                              void* d_out, int out_size, void* d_ws, size_t ws_size,
                              hipStream_t stream) {
    const float* lat  = (const float*)d_in[0];
    const float* nman = (const float*)d_in[1];
    const float* len  = (const float*)d_in[2];
    const float* slp  = (const float*)d_in[3];
    const float* wcf  = (const float*)d_in[4];
    const float* wex  = (const float*)d_in[5];
    const float* dcf  = (const float*)d_in[6];
    const float* dex  = (const float*)d_in[7];
    const int*   dtp  = (const int*)d_in[8];
    float* out = (float*)d_out;

    if (ws_size >= REQ_BYTES) {
        float* ws = (float*)d_ws;
        unsigned int* flags = (unsigned int*)(ws + FLAGS_FOFF);
        zero_flags<<<dim3(1), dim3(512), 0, stream>>>(flags);
        pipe_kernel<<<dim3(NBLK), dim3(PIPE_THREADS), 0, stream>>>(
            lat, nman, len, slp, wcf, wex, dcf, dex, dtp, out, ws);
    } else {
        route_kernel<<<dim3(1), dim3(NTHREADS), 0, stream>>>(
            lat, nman, len, slp, wcf, wex, dcf, dex, dtp, out);
    }
}

// Round 3
// 1182.724 us; speedup vs baseline: 10.1375x; 1.4778x over previous
//
#include <hip/hip_runtime.h>

// Muskingum-Cunge routing on a full binary tree (heap layout), depth 13.
// N = 8191 reaches, T = 2048 timesteps. Outlet = node 0.
// Round 3: persistent cross-CU pipeline, device-coherent (IF$) data path.
//   39 blocks: L12 x16, L11 x8, L10 x4, L9 x2, L8..L0 x1 (<=256 thr each).
//   All cross-block traffic via __hip_atomic_* AGENT scope (bypasses the
//   non-coherent per-XCD L2 -> L2 stays clean -> release fence is cheap;
//   polls are relaxed loads, no invalidates).
//   BATCH=32 timesteps per handoff.
// Fallback: single-WG kernel (round-1, verified) if ws_size too small.

#define NN 8191
#define TT 2048
#define BATCH 32
#define NBLK 39
#define BTHREADS 256

#define FLAGS_FOFF 16773120ull                 // float offset of flags (reuses unused L0 buf)
#define REQ_BYTES  ((FLAGS_FOFF + NBLK * 32ull) * 4ull)   // 67,097,472

#if __has_builtin(__builtin_amdgcn_exp2f)
__device__ __forceinline__ float fexp2(float x) { return __builtin_amdgcn_exp2f(x); }
#else
__device__ __forceinline__ float fexp2(float x) { return exp2f(x); }
#endif
#if __has_builtin(__builtin_amdgcn_logf)
__device__ __forceinline__ float flog2(float x) { return __builtin_amdgcn_logf(x); }
#else
__device__ __forceinline__ float flog2(float x) { return log2f(x); }
#endif
#if __has_builtin(__builtin_amdgcn_rcpf)
__device__ __forceinline__ float frcp(float x) { return __builtin_amdgcn_rcpf(x); }
#else
__device__ __forceinline__ float frcp(float x) { return 1.0f / x; }
#endif

__device__ __forceinline__ float mc_update(float Inew, float Iold, float Oold,
                                           float cc, float e23, float wc, float we,
                                           float twoL, float SL, float dtf)
{
    float Qr = fmaxf(0.5f * (Inew + Oold), 1e-3f);
    float lg = flog2(Qr);
    float c  = fmaxf(cc * fexp2(e23 * lg), 1e-3f);
    float w  = wc * fexp2(we * lg);
    float twoK = twoL * frcp(c);
    float X = 0.5f - 0.5f * Qr * frcp(w * SL * c);
    X = fminf(fmaxf(X, 0.0f), 0.5f);
    float A = twoK * X;
    float B = twoK - A;
    float r = frcp(B + dtf);
    float C1 = (dtf - A) * r;
    float C2 = (dtf + A) * r;
    float C3 = (B - dtf) * r;
    return fmaxf(C1 * Inew + C2 * Iold + C3 * Oold, 0.0f);
}

// ---------------- stage tables (39 blocks) ----------------
__constant__ int g_level[NBLK] = {
    12,12,12,12,12,12,12,12,12,12,12,12,12,12,12,12,
    11,11,11,11,11,11,11,11,
    10,10,10,10,
    9,9,
    8,7,6,5,4,3,2,1,0};
__constant__ int g_nstart[NBLK] = {
    4095,4351,4607,4863,5119,5375,5631,5887,6143,6399,6655,6911,7167,7423,7679,7935,
    2047,2303,2559,2815,3071,3327,3583,3839,
    1023,1279,1535,1791,
    511,767,
    255,127,63,31,15,7,3,1,0};
__constant__ int g_cnt[NBLK] = {
    256,256,256,256,256,256,256,256,256,256,256,256,256,256,256,256,
    256,256,256,256,256,256,256,256,
    256,256,256,256,
    256,256,
    256,128,64,32,16,8,4,2,1};
__constant__ int g_prodA[NBLK] = {
    -1,-1,-1,-1,-1,-1,-1,-1,-1,-1,-1,-1,-1,-1,-1,-1,
    0,2,4,6,8,10,12,14,
    16,18,20,22,
    24,26,
    28,30,31,32,33,34,35,36,37};
__constant__ int g_prodB[NBLK] = {
    -1,-1,-1,-1,-1,-1,-1,-1,-1,-1,-1,-1,-1,-1,-1,-1,
    1,3,5,7,9,11,13,15,
    17,19,21,23,
    25,27,
    29,-1,-1,-1,-1,-1,-1,-1,-1};
// float offset of level-l output buffer inside ws (levels 0..12; level 0 unused)
__constant__ unsigned long long g_off[13] = {
    16773120ull, 16769024ull, 16760832ull, 16744448ull, 16711680ull,
    16646144ull, 16515072ull, 16252928ull, 15728640ull, 14680064ull,
    12582912ull, 8388608ull, 0ull};

__device__ __forceinline__ void waitflags(const unsigned int* fa, const unsigned int* fb,
                                          unsigned int target)
{
    if (!fa) return;
    while (true) {
        unsigned int a = __hip_atomic_load(fa, __ATOMIC_RELAXED, __HIP_MEMORY_SCOPE_AGENT);
        unsigned int b = fb ? __hip_atomic_load(fb, __ATOMIC_RELAXED, __HIP_MEMORY_SCOPE_AGENT)
                            : a;
        if (a >= target && b >= target) break;
        __builtin_amdgcn_s_sleep(2);
    }
}

__global__ void zero_flags(unsigned int* flags)
{
    for (int i = threadIdx.x; i < NBLK * 32; i += 256) flags[i] = 0;
}

__global__ __launch_bounds__(BTHREADS)
void pipe_kernel(const float* __restrict__ lat,
                 const float* __restrict__ nman,
                 const float* __restrict__ len,
                 const float* __restrict__ slp,
                 const float* __restrict__ wcf,
                 const float* __restrict__ wex,
                 const float* __restrict__ dcf,
                 const float* __restrict__ dex,
                 const int*   __restrict__ dtp,
                 float*       __restrict__ out,
                 float*       __restrict__ ws)
{
    const int bid = blockIdx.x;
    const int tid = threadIdx.x;
    const int lvl = g_level[bid];
    const int cnt = g_cnt[bid];
    const bool multiwave = (cnt > 64);
    if (!multiwave && tid >= 64) return;   // single-wave stages shed extra waves

    const bool active = (tid < cnt);
    const int node = g_nstart[bid] + (active ? tid : 0);
    const int ml = node - ((1 << lvl) - 1);         // local index within level

    unsigned int* flags = (unsigned int*)(ws + FLAGS_FOFF);
    unsigned int* myflag = flags + (size_t)bid * 32;
    const int pa = g_prodA[bid], pb = g_prodB[bid];
    const unsigned int* fa = (pa >= 0) ? (flags + (size_t)pa * 32) : nullptr;
    const unsigned int* fb = (pb >= 0) ? (flags + (size_t)pb * 32) : nullptr;

    const bool haschild = (lvl < 12);
    const int myW = 1 << lvl;
    const int childW = 1 << (lvl + 1);
    float* myBuf = ws + g_off[lvl];
    // child pair (2*ml, 2*ml+1) read as one 8-byte coherent load
    const unsigned long long* childBuf =
        haschild ? (const unsigned long long*)(ws + g_off[lvl + 1]) : nullptr;

    const float dtf = (float)dtp[0];

    // per-node derived constants + state (registers, persistent)
    float cc = 0, e23 = 0, wcc = 0, wee = 0, twoL = 0, SL = 0;
    float Iold = 0.0f, Oold = 0.0f;
    {
        float n = nman[node], L = len[node], S = slp[node];
        float wc = wcf[node], we = wex[node], dc = dcf[node], de = dex[node];
        float dc23 = fexp2(0.6666667f * flog2(dc));
        cc  = 1.6666667f * dc23 * sqrtf(S) * frcp(n);
        e23 = 0.6666667f * de;
        wcc = wc; wee = we;
        twoL = 2.0f * L;
        SL = S * L;
    }

    for (int t0 = 0; t0 < TT; t0 += BATCH) {
        waitflags(fa, fb, (unsigned int)(t0 + BATCH));

        if (active) {
            float la[BATCH], c0[BATCH], c1[BATCH];
#pragma unroll
            for (int k = 0; k < BATCH; ++k) {
                la[k] = lat[(size_t)(t0 + k) * NN + node];
                if (haschild) {
                    unsigned long long cv = __hip_atomic_load(
                        childBuf + ((size_t)(t0 + k) * childW >> 1) + ml,
                        __ATOMIC_RELAXED, __HIP_MEMORY_SCOPE_AGENT);
                    float2 c = *(float2*)&cv;
                    c0[k] = c.x; c1[k] = c.y;
                }
            }
#pragma unroll
            for (int k = 0; k < BATCH; ++k) {
                float Inew = la[k] + (haschild ? (c0[k] + c1[k]) : 0.0f);
                float O = mc_update(Inew, Iold, Oold, cc, e23, wcc, wee, twoL, SL, dtf);
                Iold = Inew; Oold = O;
                if (lvl > 0)
                    __hip_atomic_store(myBuf + (size_t)(t0 + k) * myW + ml, O,
                                       __ATOMIC_RELAXED, __HIP_MEMORY_SCOPE_AGENT);
                else
                    out[t0 + k] = O;
            }
        }
        if (multiwave) { __threadfence(); __syncthreads(); }
        if (tid == 0)
            __hip_atomic_store(myflag, (unsigned int)(t0 + BATCH),
                               __ATOMIC_RELEASE, __HIP_MEMORY_SCOPE_AGENT);
    }
}

// ---------------- fallback: round-1 single-WG kernel (verified) ----------------
#define NTHREADS 1024
__global__ __launch_bounds__(NTHREADS)
void route_kernel(const float* __restrict__ lat,
                  const float* __restrict__ nman,
                  const float* __restrict__ len,
                  const float* __restrict__ slp,
                  const float* __restrict__ wcf,
                  const float* __restrict__ wex,
                  const float* __restrict__ dcf,
                  const float* __restrict__ dex,
                  const int*   __restrict__ dtp,
                  float*       __restrict__ out)
{
    __shared__ float Osh[NN];
    const int tid = threadIdx.x;
    const float dtf = (float)dtp[0];

    int nodes[8];
    nodes[0] = 4095 + tid;
    nodes[1] = 5119 + tid;
    nodes[2] = 6143 + tid;
    nodes[3] = 7167 + tid;
    nodes[4] = 2047 + tid;
    nodes[5] = 3071 + tid;
    nodes[6] = 1023 + tid;
    nodes[7] = (tid < 1023) ? tid : 0;

    float cc[8], e23[8], wcc[8], wee[8], twoL[8], SL[8];
    float Ireg[8], Oreg[8];
#pragma unroll
    for (int k = 0; k < 8; ++k) {
        int i = nodes[k];
        float n = nman[i], L = len[i], S = slp[i];
        float wc = wcf[i], we = wex[i], dc = dcf[i], de = dex[i];
        float dc23 = fexp2(0.6666667f * flog2(dc));
        cc[k]  = 1.6666667f * dc23 * sqrtf(S) * frcp(n);
        e23[k] = 0.6666667f * de;
        wcc[k] = wc; wee[k] = we;
        twoL[k] = 2.0f * L;
        SL[k]  = S * L;
        Ireg[k] = 0.0f; Oreg[k] = 0.0f;
    }
    for (int i = tid; i < NN; i += NTHREADS) Osh[i] = 0.0f;
    __syncthreads();

    for (int t = 0; t < TT; ++t) {
        const float* __restrict__ latt = lat + (size_t)t * NN;
#pragma unroll
        for (int k = 0; k < 4; ++k) {
            int i = nodes[k];
            float Inew = latt[i];
            float O = mc_update(Inew, Ireg[k], Oreg[k],
                                cc[k], e23[k], wcc[k], wee[k], twoL[k], SL[k], dtf);
            Ireg[k] = Inew; Oreg[k] = O; Osh[i] = O;
        }
        __syncthreads();
#pragma unroll
        for (int k = 4; k < 6; ++k) {
            int i = nodes[k];
            float Inew = latt[i] + Osh[2 * i + 1] + Osh[2 * i + 2];
            float O = mc_update(Inew, Ireg[k], Oreg[k],
                                cc[k], e23[k], wcc[k], wee[k], twoL[k], SL[k], dtf);
            Ireg[k] = Inew; Oreg[k] = O; Osh[i] = O;
        }
        __syncthreads();
        {
            int i = nodes[6];
            float Inew = latt[i] + Osh[2 * i + 1] + Osh[2 * i + 2];
            float O = mc_update(Inew, Ireg[6], Oreg[6],
                                cc[6], e23[6], wcc[6], wee[6], twoL[6], SL[6], dtf);
            Ireg[6] = Inew; Oreg[6] = O; Osh[i] = O;
        }
        __syncthreads();
        for (int l = 9; l >= 0; --l) {
            int s = (1 << l) - 1;
            int e = (1 << (l + 1)) - 1;
            if (tid >= s && tid < e) {
                int i = tid;
                float Inew = latt[i] + Osh[2 * i + 1] + Osh[2 * i + 2];
                float O = mc_update(Inew, Ireg[7], Oreg[7],
                                    cc[7], e23[7], wcc[7], wee[7], twoL[7], SL[7], dtf);
                Ireg[7] = Inew; Oreg[7] = O; Osh[i] = O;
            }
            __syncthreads();
        }
        if (tid == 0) out[t] = Oreg[7];
    }
}

extern "C" void kernel_launch(void* const* d_in, const int* in_sizes, int n_in,
                              void* d_out, int out_size, void* d_ws, size_t ws_size,
                              hipStream_t stream) {
    const float* lat  = (const float*)d_in[0];
    const float* nman = (const float*)d_in[1];
    const float* len  = (const float*)d_in[2];
    const float* slp  = (const float*)d_in[3];
    const float* wcf  = (const float*)d_in[4];
    const float* wex  = (const float*)d_in[5];
    const float* dcf  = (const float*)d_in[6];
    const float* dex  = (const float*)d_in[7];
    const int*   dtp  = (const int*)d_in[8];
    float* out = (float*)d_out;

    if (ws_size >= REQ_BYTES) {
        float* ws = (float*)d_ws;
        unsigned int* flags = (unsigned int*)(ws + FLAGS_FOFF);
        zero_flags<<<dim3(1), dim3(256), 0, stream>>>(flags);
        pipe_kernel<<<dim3(NBLK), dim3(BTHREADS), 0, stream>>>(
            lat, nman, len, slp, wcf, wex, dcf, dex, dtp, out, ws);
    } else {
        route_kernel<<<dim3(1), dim3(NTHREADS), 0, stream>>>(
            lat, nman, len, slp, wcf, wex, dcf, dex, dtp, out);
    }
}

// Round 4
// 469.515 us; speedup vs baseline: 25.5367x; 2.5190x over previous
//
#include <hip/hip_runtime.h>

// Muskingum-Cunge routing on a full binary tree (heap layout), depth 13.
// N = 8191 reaches, T = 2048 timesteps. Outlet = node 0.
// Round 4: persistent cross-CU pipeline, fence-free handoff protocol.
//   39 blocks: L12 x16, L11 x8, L10 x4, L9 x2, L8..L0 x1 (<=256 thr each).
//   Data path: relaxed AGENT-scope atomics (sc0 sc1 -> coherency point = IF$,
//   bypasses non-coherent per-XCD L2). Publish: s_waitcnt vmcnt(0) (stores
//   acked at coherency point) -> syncthreads -> RELAXED flag store. Consume:
//   relaxed poll -> sched/compiler barrier -> coherent child loads.
//   NO buffer_wbl2 / buffer_inv anywhere in the loop (the round-3 ~16us/batch
//   fixed cost). lat[] HBM loads hoisted above the poll to hide latency.
// Fallback: single-WG kernel (round-1, verified) if ws_size too small.

#define NN 8191
#define TT 2048
#define BATCH 32
#define NBLK 39
#define BTHREADS 256

#define FLAGS_FOFF 16773120ull                 // float offset of flags (reuses unused L0 buf)
#define REQ_BYTES  ((FLAGS_FOFF + NBLK * 32ull) * 4ull)   // 67,097,472

#if __has_builtin(__builtin_amdgcn_exp2f)
__device__ __forceinline__ float fexp2(float x) { return __builtin_amdgcn_exp2f(x); }
#else
__device__ __forceinline__ float fexp2(float x) { return exp2f(x); }
#endif
#if __has_builtin(__builtin_amdgcn_logf)
__device__ __forceinline__ float flog2(float x) { return __builtin_amdgcn_logf(x); }
#else
__device__ __forceinline__ float flog2(float x) { return log2f(x); }
#endif
#if __has_builtin(__builtin_amdgcn_rcpf)
__device__ __forceinline__ float frcp(float x) { return __builtin_amdgcn_rcpf(x); }
#else
__device__ __forceinline__ float frcp(float x) { return 1.0f / x; }
#endif

__device__ __forceinline__ float mc_update(float Inew, float Iold, float Oold,
                                           float cc, float e23, float wc, float we,
                                           float twoL, float SL, float dtf)
{
    float Qr = fmaxf(0.5f * (Inew + Oold), 1e-3f);
    float lg = flog2(Qr);
    float c  = fmaxf(cc * fexp2(e23 * lg), 1e-3f);
    float w  = wc * fexp2(we * lg);
    float twoK = twoL * frcp(c);
    float X = 0.5f - 0.5f * Qr * frcp(w * SL * c);
    X = fminf(fmaxf(X, 0.0f), 0.5f);
    float A = twoK * X;
    float B = twoK - A;
    float r = frcp(B + dtf);
    float C1 = (dtf - A) * r;
    float C2 = (dtf + A) * r;
    float C3 = (B - dtf) * r;
    return fmaxf(C1 * Inew + C2 * Iold + C3 * Oold, 0.0f);
}

// ---------------- stage tables (39 blocks) ----------------
__constant__ int g_level[NBLK] = {
    12,12,12,12,12,12,12,12,12,12,12,12,12,12,12,12,
    11,11,11,11,11,11,11,11,
    10,10,10,10,
    9,9,
    8,7,6,5,4,3,2,1,0};
__constant__ int g_nstart[NBLK] = {
    4095,4351,4607,4863,5119,5375,5631,5887,6143,6399,6655,6911,7167,7423,7679,7935,
    2047,2303,2559,2815,3071,3327,3583,3839,
    1023,1279,1535,1791,
    511,767,
    255,127,63,31,15,7,3,1,0};
__constant__ int g_cnt[NBLK] = {
    256,256,256,256,256,256,256,256,256,256,256,256,256,256,256,256,
    256,256,256,256,256,256,256,256,
    256,256,256,256,
    256,256,
    256,128,64,32,16,8,4,2,1};
__constant__ int g_prodA[NBLK] = {
    -1,-1,-1,-1,-1,-1,-1,-1,-1,-1,-1,-1,-1,-1,-1,-1,
    0,2,4,6,8,10,12,14,
    16,18,20,22,
    24,26,
    28,30,31,32,33,34,35,36,37};
__constant__ int g_prodB[NBLK] = {
    -1,-1,-1,-1,-1,-1,-1,-1,-1,-1,-1,-1,-1,-1,-1,-1,
    1,3,5,7,9,11,13,15,
    17,19,21,23,
    25,27,
    29,-1,-1,-1,-1,-1,-1,-1,-1};
// float offset of level-l output buffer inside ws (levels 0..12; level 0 unused)
__constant__ unsigned long long g_off[13] = {
    16773120ull, 16769024ull, 16760832ull, 16744448ull, 16711680ull,
    16646144ull, 16515072ull, 16252928ull, 15728640ull, 14680064ull,
    12582912ull, 8388608ull, 0ull};

__device__ __forceinline__ void waitflags(const unsigned int* fa, const unsigned int* fb,
                                          unsigned int target)
{
    if (!fa) return;
    while (true) {
        unsigned int a = __hip_atomic_load(fa, __ATOMIC_RELAXED, __HIP_MEMORY_SCOPE_AGENT);
        unsigned int b = fb ? __hip_atomic_load(fb, __ATOMIC_RELAXED, __HIP_MEMORY_SCOPE_AGENT)
                            : a;
        if (a >= target && b >= target) break;
        __builtin_amdgcn_s_sleep(2);
    }
    // Keep subsequent coherent loads from being hoisted above the poll.
    __builtin_amdgcn_sched_barrier(0);
    asm volatile("" ::: "memory");
}

__global__ void zero_flags(unsigned int* flags)
{
    for (int i = threadIdx.x; i < NBLK * 32; i += 256) flags[i] = 0;
}

__global__ __launch_bounds__(BTHREADS)
void pipe_kernel(const float* __restrict__ lat,
                 const float* __restrict__ nman,
                 const float* __restrict__ len,
                 const float* __restrict__ slp,
                 const float* __restrict__ wcf,
                 const float* __restrict__ wex,
                 const float* __restrict__ dcf,
                 const float* __restrict__ dex,
                 const int*   __restrict__ dtp,
                 float*       __restrict__ out,
                 float*       __restrict__ ws)
{
    const int bid = blockIdx.x;
    const int tid = threadIdx.x;
    const int lvl = g_level[bid];
    const int cnt = g_cnt[bid];
    const bool multiwave = (cnt > 64);
    if (!multiwave && tid >= 64) return;   // single-wave stages shed extra waves

    const bool active = (tid < cnt);
    const int node = g_nstart[bid] + (active ? tid : 0);
    const int ml = node - ((1 << lvl) - 1);         // local index within level

    unsigned int* flags = (unsigned int*)(ws + FLAGS_FOFF);
    unsigned int* myflag = flags + (size_t)bid * 32;
    const int pa = g_prodA[bid], pb = g_prodB[bid];
    const unsigned int* fa = (pa >= 0) ? (flags + (size_t)pa * 32) : nullptr;
    const unsigned int* fb = (pb >= 0) ? (flags + (size_t)pb * 32) : nullptr;

    const bool haschild = (lvl < 12);
    const int myW = 1 << lvl;
    const int childW = 1 << (lvl + 1);
    float* myBuf = ws + g_off[lvl];
    // child pair (2*ml, 2*ml+1) read as one 8-byte coherent load
    const unsigned long long* childBuf =
        haschild ? (const unsigned long long*)(ws + g_off[lvl + 1]) : nullptr;

    const float dtf = (float)dtp[0];

    // per-node derived constants + state (registers, persistent)
    float cc = 0, e23 = 0, wcc = 0, wee = 0, twoL = 0, SL = 0;
    float Iold = 0.0f, Oold = 0.0f;
    {
        float n = nman[node], L = len[node], S = slp[node];
        float wc = wcf[node], we = wex[node], dc = dcf[node], de = dex[node];
        float dc23 = fexp2(0.6666667f * flog2(dc));
        cc  = 1.6666667f * dc23 * sqrtf(S) * frcp(n);
        e23 = 0.6666667f * de;
        wcc = wc; wee = we;
        twoL = 2.0f * L;
        SL = S * L;
    }

    for (int t0 = 0; t0 < TT; t0 += BATCH) {
        // lat loads are flag-independent: issue BEFORE the poll so HBM latency
        // hides under the wait.
        float la[BATCH];
        if (active) {
#pragma unroll
            for (int k = 0; k < BATCH; ++k)
                la[k] = lat[(size_t)(t0 + k) * NN + node];
        }

        waitflags(fa, fb, (unsigned int)(t0 + BATCH));

        if (active) {
            float c0[BATCH], c1[BATCH];
            if (haschild) {
#pragma unroll
                for (int k = 0; k < BATCH; ++k) {
                    unsigned long long cv = __hip_atomic_load(
                        childBuf + ((size_t)(t0 + k) * childW >> 1) + ml,
                        __ATOMIC_RELAXED, __HIP_MEMORY_SCOPE_AGENT);
                    float2 c = *(float2*)&cv;
                    c0[k] = c.x; c1[k] = c.y;
                }
            }
#pragma unroll
            for (int k = 0; k < BATCH; ++k) {
                float Inew = la[k] + (haschild ? (c0[k] + c1[k]) : 0.0f);
                float O = mc_update(Inew, Iold, Oold, cc, e23, wcc, wee, twoL, SL, dtf);
                Iold = Inew; Oold = O;
                if (lvl > 0)
                    __hip_atomic_store(myBuf + (size_t)(t0 + k) * myW + ml, O,
                                       __ATOMIC_RELAXED, __HIP_MEMORY_SCOPE_AGENT);
                else
                    out[t0 + k] = O;
            }
        }
        // Publish without cache maintenance: wait until our coherent stores are
        // acked at the coherency point, sync waves, then RELAXED flag bump.
        asm volatile("s_waitcnt vmcnt(0)" ::: "memory");
        if (multiwave) __syncthreads();
        if (tid == 0)
            __hip_atomic_store(myflag, (unsigned int)(t0 + BATCH),
                               __ATOMIC_RELAXED, __HIP_MEMORY_SCOPE_AGENT);
    }
}

// ---------------- fallback: round-1 single-WG kernel (verified) ----------------
#define NTHREADS 1024
__global__ __launch_bounds__(NTHREADS)
void route_kernel(const float* __restrict__ lat,
                  const float* __restrict__ nman,
                  const float* __restrict__ len,
                  const float* __restrict__ slp,
                  const float* __restrict__ wcf,
                  const float* __restrict__ wex,
                  const float* __restrict__ dcf,
                  const float* __restrict__ dex,
                  const int*   __restrict__ dtp,
                  float*       __restrict__ out)
{
    __shared__ float Osh[NN];
    const int tid = threadIdx.x;
    const float dtf = (float)dtp[0];

    int nodes[8];
    nodes[0] = 4095 + tid;
    nodes[1] = 5119 + tid;
    nodes[2] = 6143 + tid;
    nodes[3] = 7167 + tid;
    nodes[4] = 2047 + tid;
    nodes[5] = 3071 + tid;
    nodes[6] = 1023 + tid;
    nodes[7] = (tid < 1023) ? tid : 0;

    float cc[8], e23[8], wcc[8], wee[8], twoL[8], SL[8];
    float Ireg[8], Oreg[8];
#pragma unroll
    for (int k = 0; k < 8; ++k) {
        int i = nodes[k];
        float n = nman[i], L = len[i], S = slp[i];
        float wc = wcf[i], we = wex[i], dc = dcf[i], de = dex[i];
        float dc23 = fexp2(0.6666667f * flog2(dc));
        cc[k]  = 1.6666667f * dc23 * sqrtf(S) * frcp(n);
        e23[k] = 0.6666667f * de;
        wcc[k] = wc; wee[k] = we;
        twoL[k] = 2.0f * L;
        SL[k]  = S * L;
        Ireg[k] = 0.0f; Oreg[k] = 0.0f;
    }
    for (int i = tid; i < NN; i += NTHREADS) Osh[i] = 0.0f;
    __syncthreads();

    for (int t = 0; t < TT; ++t) {
        const float* __restrict__ latt = lat + (size_t)t * NN;
#pragma unroll
        for (int k = 0; k < 4; ++k) {
            int i = nodes[k];
            float Inew = latt[i];
            float O = mc_update(Inew, Ireg[k], Oreg[k],
                                cc[k], e23[k], wcc[k], wee[k], twoL[k], SL[k], dtf);
            Ireg[k] = Inew; Oreg[k] = O; Osh[i] = O;
        }
        __syncthreads();
#pragma unroll
        for (int k = 4; k < 6; ++k) {
            int i = nodes[k];
            float Inew = latt[i] + Osh[2 * i + 1] + Osh[2 * i + 2];
            float O = mc_update(Inew, Ireg[k], Oreg[k],
                                cc[k], e23[k], wcc[k], wee[k], twoL[k], SL[k], dtf);
            Ireg[k] = Inew; Oreg[k] = O; Osh[i] = O;
        }
        __syncthreads();
        {
            int i = nodes[6];
            float Inew = latt[i] + Osh[2 * i + 1] + Osh[2 * i + 2];
            float O = mc_update(Inew, Ireg[6], Oreg[6],
                                cc[6], e23[6], wcc[6], wee[6], twoL[6], SL[6], dtf);
            Ireg[6] = Inew; Oreg[6] = O; Osh[i] = O;
        }
        __syncthreads();
        for (int l = 9; l >= 0; --l) {
            int s = (1 << l) - 1;
            int e = (1 << (l + 1)) - 1;
            if (tid >= s && tid < e) {
                int i = tid;
                float Inew = latt[i] + Osh[2 * i + 1] + Osh[2 * i + 2];
                float O = mc_update(Inew, Ireg[7], Oreg[7],
                                    cc[7], e23[7], wcc[7], wee[7], twoL[7], SL[7], dtf);
                Ireg[7] = Inew; Oreg[7] = O; Osh[i] = O;
            }
            __syncthreads();
        }
        if (tid == 0) out[t] = Oreg[7];
    }
}

extern "C" void kernel_launch(void* const* d_in, const int* in_sizes, int n_in,
                              void* d_out, int out_size, void* d_ws, size_t ws_size,
                              hipStream_t stream) {
    const float* lat  = (const float*)d_in[0];
    const float* nman = (const float*)d_in[1];
    const float* len  = (const float*)d_in[2];
    const float* slp  = (const float*)d_in[3];
    const float* wcf  = (const float*)d_in[4];
    const float* wex  = (const float*)d_in[5];
    const float* dcf  = (const float*)d_in[6];
    const float* dex  = (const float*)d_in[7];
    const int*   dtp  = (const int*)d_in[8];
    float* out = (float*)d_out;

    if (ws_size >= REQ_BYTES) {
        float* ws = (float*)d_ws;
        unsigned int* flags = (unsigned int*)(ws + FLAGS_FOFF);
        zero_flags<<<dim3(1), dim3(256), 0, stream>>>(flags);
        pipe_kernel<<<dim3(NBLK), dim3(BTHREADS), 0, stream>>>(
            lat, nman, len, slp, wcf, wex, dcf, dex, dtp, out, ws);
    } else {
        route_kernel<<<dim3(1), dim3(NTHREADS), 0, stream>>>(
            lat, nman, len, slp, wcf, wex, dcf, dex, dtp, out);
    }
}